// Round 16
// baseline (218.717 us; speedup 1.0000x reference)
//
#include <hip/hip_runtime.h>
#include <math.h>

#define BATCH 32
#define H 512
#define W 512
#define PAD 15
#define BAND 8                        /* rows per block */
#define NBANDS (H / BAND)             /* 64 */
#define NBLOCKS (BATCH * NBANDS)      /* 2048 */
#define NPART (NBLOCKS * 4)           /* 8192 wave partials */
#define NXCD 8
#define INV_KK (1.0f / 961.0f)

/* ---------- fused weight + stable BCE for one element (verified R8) ------ */
#define EMIT(tv, lv, hs)                                                      \
    {                                                                         \
        float pooled_ = (hs) * INV_KK;                                        \
        float wgt_ = fmaf(5.f, fabsf(pooled_ - (tv)), 1.f);                   \
        float al_ = fabsf(lv);                                                \
        float bce_ = fmaxf((lv), 0.f) - (lv) * (tv)                           \
                     + __logf(1.f + __expf(-al_));                            \
        num = fmaf(wgt_, bce_, num);                                          \
        den += wgt_;                                                          \
    }

/* one k-slot of the horizontal 31-window (verified bit-exact R7..R15) */
#define KSLOT(pk, pkm1, tv, lv, FIRST, LAST)                                  \
    {                                                                         \
        float hs_ = base_;                                                    \
        if (!(LAST)) {                                                        \
            float sa_ = __shfl_up(tot_ - (pk), 2);                            \
            hs_ += okm2 ? sa_ : 0.f;                                          \
        }                                                                     \
        if (!(FIRST)) {                                                       \
            float se_ = __shfl_down((pkm1), 2);                               \
            hs_ += okp2 ? se_ : 0.f;                                          \
        }                                                                     \
        EMIT(tv, lv, hs_)                                                     \
    }

#define LDG(pa, pb, ptr, yy)                                                  \
    { const float4* p_ = (const float4*)((ptr) + (size_t)(yy) * W + x0);      \
      pa = p_[0]; pb = p_[1]; }

/* full row: LDS vertical sums + t/l loads + horizontal window + BCE. */
#define ROWPASS(r)                                                            \
    {                                                                         \
        float4 A_ = ((const float4*)vs[(r)])[2 * lane];                       \
        float4 B_ = ((const float4*)vs[(r)])[2 * lane + 1];                   \
        float4 Ta_, Tb_, La_, Lb_;                                            \
        LDG(Ta_, Tb_, tb, y0 + (r)) LDG(La_, Lb_, lb, y0 + (r))               \
        const float p0_ = A_.x;                                               \
        const float p1_ = p0_ + A_.y;                                         \
        const float p2_ = p1_ + A_.z;                                         \
        const float p3_ = p2_ + A_.w;                                         \
        const float p4_ = p3_ + B_.x;                                         \
        const float p5_ = p4_ + B_.y;                                         \
        const float p6_ = p5_ + B_.z;                                         \
        const float tot_ = p6_ + B_.w;                                        \
        const float bm_ = __shfl_up(tot_, 1);                                 \
        const float dp_ = __shfl_down(tot_, 1);                               \
        const float base_ = (okm1 ? bm_ : 0.f) + tot_ + (okp1 ? dp_ : 0.f);   \
        KSLOT(p0_, 0.f, Ta_.x, La_.x, 1, 0)                                   \
        KSLOT(p1_, p0_, Ta_.y, La_.y, 0, 0)                                   \
        KSLOT(p2_, p1_, Ta_.z, La_.z, 0, 0)                                   \
        KSLOT(p3_, p2_, Ta_.w, La_.w, 0, 0)                                   \
        KSLOT(p4_, p3_, Tb_.x, Lb_.x, 0, 0)                                   \
        KSLOT(p5_, p4_, Tb_.y, Lb_.y, 0, 0)                                   \
        KSLOT(p6_, p5_, Tb_.z, Lb_.z, 0, 0)                                   \
        KSLOT(0.f, p6_, Tb_.w, Lb_.w, 0, 1)                                   \
    }

/* ---------- Phase 1: vertical running windows into LDS ------------------ */
/* thread owns columns tid and tid+256; G=1 -> interior band, no guards.
   No sched_barriers: compiler free to cluster all loads (deep MLP).        */
#define P1_INIT(G, C0, C1)                                                    \
    _Pragma("unroll")                                                         \
    for (int c = (C0); c < (C1); ++c) {                                       \
        const int y = y0 + c - PAD;                                           \
        float a0 = 0.f, a1 = 0.f;                                             \
        if ((G) || (unsigned)y < (unsigned)H) {                               \
            a0 = tcol[y * W]; a1 = tcol[y * W + 256];                         \
        }                                                                     \
        run0 += a0; run1 += a1;                                               \
    }

#define P1_SLIDE(G, J0, J1)                                                   \
    _Pragma("unroll")                                                         \
    for (int j = (J0); j < (J1); ++j) {                                       \
        vs[j][tid] = run0; vs[j][tid + 256] = run1;                           \
        if (j < BAND - 1) {                                                   \
            const int ye = y0 + j + PAD + 1, yl = y0 + j - PAD;               \
            float e0 = 0.f, e1 = 0.f, s0 = 0.f, s1 = 0.f;                     \
            if ((G) || (unsigned)ye < (unsigned)H) {                          \
                e0 = tcol[ye * W]; e1 = tcol[ye * W + 256];                   \
            }                                                                 \
            if ((G) || (unsigned)yl < (unsigned)H) {                          \
                s0 = tcol[yl * W]; s1 = tcol[yl * W + 256];                   \
            }                                                                 \
            run0 += e0 - s0; run1 += e1 - s1;                                 \
        }                                                                     \
    }

#define PHASE1(G)                                                             \
    P1_INIT(G, 0, 31)                                                         \
    P1_SLIDE(G, 0, 8)

__global__ __launch_bounds__(256)
void wbce_band_kernel(const float* __restrict__ logits,
                      const float* __restrict__ targets,
                      float2* __restrict__ partials,
                      unsigned* __restrict__ counter,
                      float* __restrict__ out) {
    __shared__ __align__(16) float vs[BAND][W];   /* 16 KB */
    __shared__ float rsum[32];
    __shared__ unsigned old_s;

    const int tid  = threadIdx.x;
    const int lane = tid & 63;
    const int w    = tid >> 6;

    /* XCD-aware bijective swizzle: 256 consecutive blocks (4 images) per XCD */
    const int bid  = (int)blockIdx.x;
    const int sbid = (bid & (NXCD - 1)) * (NBLOCKS / NXCD) + (bid >> 3);

    const int img  = sbid >> 6;            /* sbid / NBANDS */
    const int band = sbid & (NBANDS - 1);
    const int y0   = band * BAND;
    const int x0   = lane * 8;

    const float* tb = targets + (size_t)img * H * W;
    const float* lb = logits  + (size_t)img * H * W;
    const float* tcol = tb + tid;

    /* ---- Phase 1: cooperative vertical 31-row windows -> LDS ---- */
    float run0 = 0.f, run1 = 0.f;
    if (y0 >= PAD && y0 + BAND + PAD - 1 < H) {
        PHASE1(1)
    } else {
        PHASE1(0)
    }
    __syncthreads();

    /* ---- Phase 2: horizontal window + fused weight/BCE (wave = 2 rows) ---- */
    const bool okm2 = lane >= 2, okm1 = lane >= 1;
    const bool okp1 = lane <= 62, okp2 = lane <= 61;
    float num = 0.f, den = 0.f;

    const int jw = w * 2;
    ROWPASS(jw)
    ROWPASS(jw + 1)

    /* ---- wave reduction, one partial pair per wave ---- */
    #pragma unroll
    for (int off = 32; off > 0; off >>= 1) {
        num += __shfl_down(num, off);
        den += __shfl_down(den, off);
    }
    if (lane == 0) {
        partials[sbid * 4 + w] = make_float2(num, den);
    }

    /* ---- fused finalize: last block (mod-counter, any start value) ---- */
    __threadfence();                       /* release partials device-wide */
    if (tid == 0) old_s = atomicAdd(counter, 1u);
    __syncthreads();
    if ((old_s & (NBLOCKS - 1)) == (NBLOCKS - 1)) {
        __threadfence();                   /* acquire partials */
        const int fimg = tid >> 3;         /* 32 images x 8 threads */
        const int slot = tid & 7;
        float n = 0.f, d = 0.f;
        #pragma unroll
        for (int k = 0; k < 32; ++k) {
            float2 p = partials[fimg * 256 + k * 8 + slot];
            n += p.x; d += p.y;
        }
        #pragma unroll
        for (int off = 4; off > 0; off >>= 1) {
            n += __shfl_down(n, off);
            d += __shfl_down(d, off);
        }
        if (slot == 0) rsum[fimg] = n / d;
        __syncthreads();
        if (tid == 0) {
            float s = 0.f;
            #pragma unroll
            for (int i = 0; i < 32; ++i) s += rsum[i];
            out[0] = s / (float)BATCH;
        }
    }
}

extern "C" void kernel_launch(void* const* d_in, const int* in_sizes, int n_in,
                              void* d_out, int out_size, void* d_ws, size_t ws_size,
                              hipStream_t stream) {
    const float* logits  = (const float*)d_in[0];
    const float* targets = (const float*)d_in[1];
    float* out = (float*)d_out;

    float2*   partials = (float2*)d_ws;                       /* 64 KB */
    unsigned* counter  = (unsigned*)((char*)d_ws + NPART * sizeof(float2));

    wbce_band_kernel<<<NBLOCKS, 256, 0, stream>>>(logits, targets,
                                                  partials, counter, out);
}

// Round 17
// 214.557 us; speedup vs baseline: 1.0194x; 1.0194x over previous
//
#include <hip/hip_runtime.h>
#include <math.h>

#define BATCH 32
#define H 512
#define W 512
#define PAD 15
#define BAND 8                        /* rows per block */
#define NBANDS (H / BAND)             /* 64 */
#define NBLOCKS (BATCH * NBANDS)      /* 2048 */
#define NPART (NBLOCKS * 4)           /* 8192 wave partials */
#define NXCD 8
#define INV_KK (1.0f / 961.0f)

/* ---------- fused weight + stable BCE for one element (verified R8) ------ */
#define EMIT(tv, lv, hs)                                                      \
    {                                                                         \
        float pooled_ = (hs) * INV_KK;                                        \
        float wgt_ = fmaf(5.f, fabsf(pooled_ - (tv)), 1.f);                   \
        float al_ = fabsf(lv);                                                \
        float bce_ = fmaxf((lv), 0.f) - (lv) * (tv)                           \
                     + __logf(1.f + __expf(-al_));                            \
        num = fmaf(wgt_, bce_, num);                                          \
        den += wgt_;                                                          \
    }

/* one k-slot of the horizontal 31-window (verified bit-exact R7..R16) */
#define KSLOT(pk, pkm1, tv, lv, FIRST, LAST)                                  \
    {                                                                         \
        float hs_ = base_;                                                    \
        if (!(LAST)) {                                                        \
            float sa_ = __shfl_up(tot_ - (pk), 2);                            \
            hs_ += okm2 ? sa_ : 0.f;                                          \
        }                                                                     \
        if (!(FIRST)) {                                                       \
            float se_ = __shfl_down((pkm1), 2);                               \
            hs_ += okp2 ? se_ : 0.f;                                          \
        }                                                                     \
        EMIT(tv, lv, hs_)                                                     \
    }

#define LDG(pa, pb, ptr, yy)                                                  \
    { const float4* p_ = (const float4*)((ptr) + (size_t)(yy) * W + x0);      \
      pa = p_[0]; pb = p_[1]; }

/* full row: LDS vertical sums + t/l loads + horizontal window + BCE. */
#define ROWPASS(r)                                                            \
    {                                                                         \
        float4 A_ = ((const float4*)vs[(r)])[2 * lane];                       \
        float4 B_ = ((const float4*)vs[(r)])[2 * lane + 1];                   \
        float4 Ta_, Tb_, La_, Lb_;                                            \
        LDG(Ta_, Tb_, tb, y0 + (r)) LDG(La_, Lb_, lb, y0 + (r))               \
        const float p0_ = A_.x;                                               \
        const float p1_ = p0_ + A_.y;                                         \
        const float p2_ = p1_ + A_.z;                                         \
        const float p3_ = p2_ + A_.w;                                         \
        const float p4_ = p3_ + B_.x;                                         \
        const float p5_ = p4_ + B_.y;                                         \
        const float p6_ = p5_ + B_.z;                                         \
        const float tot_ = p6_ + B_.w;                                        \
        const float bm_ = __shfl_up(tot_, 1);                                 \
        const float dp_ = __shfl_down(tot_, 1);                               \
        const float base_ = (okm1 ? bm_ : 0.f) + tot_ + (okp1 ? dp_ : 0.f);   \
        KSLOT(p0_, 0.f, Ta_.x, La_.x, 1, 0)                                   \
        KSLOT(p1_, p0_, Ta_.y, La_.y, 0, 0)                                   \
        KSLOT(p2_, p1_, Ta_.z, La_.z, 0, 0)                                   \
        KSLOT(p3_, p2_, Ta_.w, La_.w, 0, 0)                                   \
        KSLOT(p4_, p3_, Tb_.x, Lb_.x, 0, 0)                                   \
        KSLOT(p5_, p4_, Tb_.y, Lb_.y, 0, 0)                                   \
        KSLOT(p6_, p5_, Tb_.z, Lb_.z, 0, 0)                                   \
        KSLOT(0.f, p6_, Tb_.w, Lb_.w, 0, 1)                                   \
    }

/* ---------- Phase 1: vertical running windows into LDS (R15 champion) --- */
/* thread owns columns tid and tid+256; G=1 -> interior band, no guards.
   sched_barrier chunking is LOAD-BEARING: it forces clustered load issue
   (R16 removed them -> VGPR 44, serial chain, 12x slowdown).               */
#define P1_INIT(G, C0, C1)                                                    \
    _Pragma("unroll")                                                         \
    for (int c = (C0); c < (C1); ++c) {                                       \
        const int y = y0 + c - PAD;                                           \
        float a0 = 0.f, a1 = 0.f;                                             \
        if ((G) || (unsigned)y < (unsigned)H) {                               \
            a0 = tcol[y * W]; a1 = tcol[y * W + 256];                         \
        }                                                                     \
        run0 += a0; run1 += a1;                                               \
    }

#define P1_SLIDE(G, J0, J1)                                                   \
    _Pragma("unroll")                                                         \
    for (int j = (J0); j < (J1); ++j) {                                       \
        vs[j][tid] = run0; vs[j][tid + 256] = run1;                           \
        if (j < BAND - 1) {                                                   \
            const int ye = y0 + j + PAD + 1, yl = y0 + j - PAD;               \
            float e0 = 0.f, e1 = 0.f, s0 = 0.f, s1 = 0.f;                     \
            if ((G) || (unsigned)ye < (unsigned)H) {                          \
                e0 = tcol[ye * W]; e1 = tcol[ye * W + 256];                   \
            }                                                                 \
            if ((G) || (unsigned)yl < (unsigned)H) {                          \
                s0 = tcol[yl * W]; s1 = tcol[yl * W + 256];                   \
            }                                                                 \
            run0 += e0 - s0; run1 += e1 - s1;                                 \
        }                                                                     \
    }

#define PHASE1(G)                                                             \
    P1_INIT(G, 0, 8)   __builtin_amdgcn_sched_barrier(0);                     \
    P1_INIT(G, 8, 16)  __builtin_amdgcn_sched_barrier(0);                     \
    P1_INIT(G, 16, 24) __builtin_amdgcn_sched_barrier(0);                     \
    P1_INIT(G, 24, 31) __builtin_amdgcn_sched_barrier(0);                     \
    P1_SLIDE(G, 0, 4)  __builtin_amdgcn_sched_barrier(0);                     \
    P1_SLIDE(G, 4, 8)

__global__ __launch_bounds__(256)
void wbce_band_kernel(const float* __restrict__ logits,
                      const float* __restrict__ targets,
                      float2* __restrict__ partials,
                      unsigned* __restrict__ counter,
                      float* __restrict__ out) {
    __shared__ __align__(16) float vs[BAND][W];   /* 16 KB */
    __shared__ float rsum[32];
    __shared__ unsigned old_s;

    const int tid  = threadIdx.x;
    const int lane = tid & 63;
    const int w    = tid >> 6;

    /* XCD-aware bijective swizzle: 256 consecutive blocks (4 images) per XCD */
    const int bid  = (int)blockIdx.x;
    const int sbid = (bid & (NXCD - 1)) * (NBLOCKS / NXCD) + (bid >> 3);

    const int img  = sbid >> 6;            /* sbid / NBANDS */
    const int band = sbid & (NBANDS - 1);
    const int y0   = band * BAND;
    const int x0   = lane * 8;

    const float* tb = targets + (size_t)img * H * W;
    const float* lb = logits  + (size_t)img * H * W;
    const float* tcol = tb + tid;

    /* ---- Phase 1: cooperative vertical 31-row windows -> LDS ---- */
    float run0 = 0.f, run1 = 0.f;
    if (y0 >= PAD && y0 + BAND + PAD - 1 < H) {
        PHASE1(1)
    } else {
        PHASE1(0)
    }
    __syncthreads();

    /* ---- Phase 2: horizontal window + fused weight/BCE (wave = 2 rows) ---- */
    const bool okm2 = lane >= 2, okm1 = lane >= 1;
    const bool okp1 = lane <= 62, okp2 = lane <= 61;
    float num = 0.f, den = 0.f;

    const int jw = w * 2;
    ROWPASS(jw)
    ROWPASS(jw + 1)

    /* ---- wave reduction, one partial pair per wave ---- */
    #pragma unroll
    for (int off = 32; off > 0; off >>= 1) {
        num += __shfl_down(num, off);
        den += __shfl_down(den, off);
    }
    if (lane == 0) {
        partials[sbid * 4 + w] = make_float2(num, den);
    }

    /* ---- fused finalize: last block (mod-counter, any start value) ---- */
    __threadfence();                       /* release partials device-wide */
    if (tid == 0) old_s = atomicAdd(counter, 1u);
    __syncthreads();
    if ((old_s & (NBLOCKS - 1)) == (NBLOCKS - 1)) {
        __threadfence();                   /* acquire partials */
        const int fimg = tid >> 3;         /* 32 images x 8 threads */
        const int slot = tid & 7;
        float n = 0.f, d = 0.f;
        #pragma unroll
        for (int k = 0; k < 32; ++k) {
            float2 p = partials[fimg * 256 + k * 8 + slot];
            n += p.x; d += p.y;
        }
        #pragma unroll
        for (int off = 4; off > 0; off >>= 1) {
            n += __shfl_down(n, off);
            d += __shfl_down(d, off);
        }
        if (slot == 0) rsum[fimg] = n / d;
        __syncthreads();
        if (tid == 0) {
            float s = 0.f;
            #pragma unroll
            for (int i = 0; i < 32; ++i) s += rsum[i];
            out[0] = s / (float)BATCH;
        }
    }
}

extern "C" void kernel_launch(void* const* d_in, const int* in_sizes, int n_in,
                              void* d_out, int out_size, void* d_ws, size_t ws_size,
                              hipStream_t stream) {
    const float* logits  = (const float*)d_in[0];
    const float* targets = (const float*)d_in[1];
    float* out = (float*)d_out;

    float2*   partials = (float2*)d_ws;                       /* 64 KB */
    unsigned* counter  = (unsigned*)((char*)d_ws + NPART * sizeof(float2));

    wbce_band_kernel<<<NBLOCKS, 256, 0, stream>>>(logits, targets,
                                                  partials, counter, out);
}

// Round 18
// 24.047 us; speedup vs baseline: 9.0954x; 8.9225x over previous
//
#include <hip/hip_runtime.h>
#include <math.h>

#define BATCH 32
#define H 512
#define W 512
#define PAD 15
#define BAND 8                        /* rows per block */
#define NBANDS (H / BAND)             /* 64 */
#define NBLOCKS (BATCH * NBANDS)      /* 2048 */
#define NTHREADS 512                  /* 8 waves: 1 row/wave, 1 col/thread */
#define NPART (NBLOCKS * 8)           /* 16384 wave partials */
#define NXCD 8
#define INV_KK (1.0f / 961.0f)

/* ---------- fused weight + stable BCE for one element (verified R8) ------ */
#define EMIT(tv, lv, hs)                                                      \
    {                                                                         \
        float pooled_ = (hs) * INV_KK;                                        \
        float wgt_ = fmaf(5.f, fabsf(pooled_ - (tv)), 1.f);                   \
        float al_ = fabsf(lv);                                                \
        float bce_ = fmaxf((lv), 0.f) - (lv) * (tv)                           \
                     + __logf(1.f + __expf(-al_));                            \
        num = fmaf(wgt_, bce_, num);                                          \
        den += wgt_;                                                          \
    }

/* one k-slot of the horizontal 31-window (verified bit-exact R7..R17) */
#define KSLOT(pk, pkm1, tv, lv, FIRST, LAST)                                  \
    {                                                                         \
        float hs_ = base_;                                                    \
        if (!(LAST)) {                                                        \
            float sa_ = __shfl_up(tot_ - (pk), 2);                            \
            hs_ += okm2 ? sa_ : 0.f;                                          \
        }                                                                     \
        if (!(FIRST)) {                                                       \
            float se_ = __shfl_down((pkm1), 2);                               \
            hs_ += okp2 ? se_ : 0.f;                                          \
        }                                                                     \
        EMIT(tv, lv, hs_)                                                     \
    }

#define LDG(pa, pb, ptr, yy)                                                  \
    { const float4* p_ = (const float4*)((ptr) + (size_t)(yy) * W + x0);      \
      pa = p_[0]; pb = p_[1]; }

/* full row: LDS vertical sums + t/l loads + horizontal window + BCE. */
#define ROWPASS(r)                                                            \
    {                                                                         \
        float4 A_ = ((const float4*)vs[(r)])[2 * lane];                       \
        float4 B_ = ((const float4*)vs[(r)])[2 * lane + 1];                   \
        float4 Ta_, Tb_, La_, Lb_;                                            \
        LDG(Ta_, Tb_, tb, y0 + (r)) LDG(La_, Lb_, lb, y0 + (r))               \
        const float p0_ = A_.x;                                               \
        const float p1_ = p0_ + A_.y;                                         \
        const float p2_ = p1_ + A_.z;                                         \
        const float p3_ = p2_ + A_.w;                                         \
        const float p4_ = p3_ + B_.x;                                         \
        const float p5_ = p4_ + B_.y;                                         \
        const float p6_ = p5_ + B_.z;                                         \
        const float tot_ = p6_ + B_.w;                                        \
        const float bm_ = __shfl_up(tot_, 1);                                 \
        const float dp_ = __shfl_down(tot_, 1);                               \
        const float base_ = (okm1 ? bm_ : 0.f) + tot_ + (okp1 ? dp_ : 0.f);   \
        KSLOT(p0_, 0.f, Ta_.x, La_.x, 1, 0)                                   \
        KSLOT(p1_, p0_, Ta_.y, La_.y, 0, 0)                                   \
        KSLOT(p2_, p1_, Ta_.z, La_.z, 0, 0)                                   \
        KSLOT(p3_, p2_, Ta_.w, La_.w, 0, 0)                                   \
        KSLOT(p4_, p3_, Tb_.x, Lb_.x, 0, 0)                                   \
        KSLOT(p5_, p4_, Tb_.y, Lb_.y, 0, 0)                                   \
        KSLOT(p6_, p5_, Tb_.z, Lb_.z, 0, 0)                                   \
        KSLOT(0.f, p6_, Tb_.w, Lb_.w, 0, 1)                                   \
    }

/* ---------- Phase 1: vertical running windows into LDS ------------------ */
/* thread owns ONE column (tid); G=1 -> interior band, no guards.
   sched_barrier chunking is LOAD-BEARING (R16: removal -> serial chain).   */
#define P1_INIT(G, C0, C1)                                                    \
    _Pragma("unroll")                                                         \
    for (int c = (C0); c < (C1); ++c) {                                       \
        const int y = y0 + c - PAD;                                           \
        float a0 = 0.f;                                                       \
        if ((G) || (unsigned)y < (unsigned)H) a0 = tcol[y * W];               \
        run0 += a0;                                                           \
    }

#define P1_SLIDE(G, J0, J1)                                                   \
    _Pragma("unroll")                                                         \
    for (int j = (J0); j < (J1); ++j) {                                       \
        vs[j][tid] = run0;                                                    \
        if (j < BAND - 1) {                                                   \
            const int ye = y0 + j + PAD + 1, yl = y0 + j - PAD;               \
            float e0 = 0.f, s0 = 0.f;                                         \
            if ((G) || (unsigned)ye < (unsigned)H) e0 = tcol[ye * W];         \
            if ((G) || (unsigned)yl < (unsigned)H) s0 = tcol[yl * W];         \
            run0 += e0 - s0;                                                  \
        }                                                                     \
    }

#define PHASE1(G)                                                             \
    P1_INIT(G, 0, 8)   __builtin_amdgcn_sched_barrier(0);                     \
    P1_INIT(G, 8, 16)  __builtin_amdgcn_sched_barrier(0);                     \
    P1_INIT(G, 16, 24) __builtin_amdgcn_sched_barrier(0);                     \
    P1_INIT(G, 24, 31) __builtin_amdgcn_sched_barrier(0);                     \
    P1_SLIDE(G, 0, 4)  __builtin_amdgcn_sched_barrier(0);                     \
    P1_SLIDE(G, 4, 8)

__global__ __launch_bounds__(NTHREADS)
void wbce_band_kernel(const float* __restrict__ logits,
                      const float* __restrict__ targets,
                      float2* __restrict__ partials) {
    __shared__ __align__(16) float vs[BAND][W];   /* 16 KB */

    const int tid  = threadIdx.x;
    const int lane = tid & 63;
    const int w    = tid >> 6;                    /* wave id 0..7 = row */

    /* XCD-aware bijective swizzle: 256 consecutive blocks (4 images) per XCD */
    const int bid  = (int)blockIdx.x;
    const int sbid = (bid & (NXCD - 1)) * (NBLOCKS / NXCD) + (bid >> 3);

    const int img  = sbid >> 6;            /* sbid / NBANDS */
    const int band = sbid & (NBANDS - 1);
    const int y0   = band * BAND;
    const int x0   = lane * 8;

    const float* tb = targets + (size_t)img * H * W;
    const float* lb = logits  + (size_t)img * H * W;
    const float* tcol = tb + tid;

    /* ---- Phase 1: cooperative vertical 31-row windows -> LDS ---- */
    float run0 = 0.f;
    if (y0 >= PAD && y0 + BAND + PAD - 1 < H) {
        PHASE1(1)
    } else {
        PHASE1(0)
    }
    __syncthreads();

    /* ---- Phase 2: horizontal window + fused weight/BCE (wave = 1 row) ---- */
    const bool okm2 = lane >= 2, okm1 = lane >= 1;
    const bool okp1 = lane <= 62, okp2 = lane <= 61;
    float num = 0.f, den = 0.f;

    ROWPASS(w)

    /* ---- wave reduction, one partial pair per wave ---- */
    #pragma unroll
    for (int off = 32; off > 0; off >>= 1) {
        num += __shfl_down(num, off);
        den += __shfl_down(den, off);
    }
    if (lane == 0) {
        partials[sbid * 8 + w] = make_float2(num, den);
    }
}

/* 16384 partial pairs -> scalar. Image i owns pairs [i*512, i*512+512). */
__global__ __launch_bounds__(1024)
void wbce_finalize_kernel(const float2* __restrict__ partials,
                          float* __restrict__ out) {
    __shared__ float rsum[16];
    const int t = threadIdx.x;
    const int img = t >> 5;
    const int j = t & 31;
    const int base = img * 512;
    float num = 0.f, den = 0.f;
    #pragma unroll
    for (int k = 0; k < 16; ++k) {
        float2 p = partials[base + j + 32 * k];
        num += p.x; den += p.y;
    }
    #pragma unroll
    for (int off = 16; off > 0; off >>= 1) {
        num += __shfl_down(num, off, 32);
        den += __shfl_down(den, off, 32);
    }
    float ratio = 0.f;
    if ((t & 31) == 0) ratio = num / den;
    ratio += __shfl_down(ratio, 32);          /* lane0 += lane32 */
    const int lane = t & 63;
    const int wv = t >> 6;
    if (lane == 0) rsum[wv] = ratio;
    __syncthreads();
    if (t == 0) {
        float s = 0.f;
        #pragma unroll
        for (int i = 0; i < 16; ++i) s += rsum[i];
        out[0] = s / (float)BATCH;
    }
}

extern "C" void kernel_launch(void* const* d_in, const int* in_sizes, int n_in,
                              void* d_out, int out_size, void* d_ws, size_t ws_size,
                              hipStream_t stream) {
    const float* logits  = (const float*)d_in[0];
    const float* targets = (const float*)d_in[1];
    float* out = (float*)d_out;
    float2* partials = (float2*)d_ws;   /* NPART float2 = 128 KB */

    wbce_band_kernel<<<NBLOCKS, NTHREADS, 0, stream>>>(logits, targets, partials);
    wbce_finalize_kernel<<<1, 1024, 0, stream>>>(partials, out);
}

// Round 19
// 23.715 us; speedup vs baseline: 9.2226x; 1.0140x over previous
//
#include <hip/hip_runtime.h>
#include <math.h>

#define BATCH 32
#define H 512
#define W 512
#define PAD 15
#define BAND 8                        /* rows per block */
#define NBANDS (H / BAND)             /* 64 */
#define NBLOCKS (BATCH * NBANDS)      /* 2048 */
#define NTHREADS 512                  /* 8 waves: 1 row/wave, 1 col/thread */
#define NPART (NBLOCKS * 8)           /* 16384 wave partials */
#define NXCD 8
#define INV_KK (1.0f / 961.0f)

/* ---------- fused weight + stable BCE for one element (verified R8) ------ */
#define EMIT(tv, lv, hs)                                                      \
    {                                                                         \
        float pooled_ = (hs) * INV_KK;                                        \
        float wgt_ = fmaf(5.f, fabsf(pooled_ - (tv)), 1.f);                   \
        float al_ = fabsf(lv);                                                \
        float bce_ = fmaxf((lv), 0.f) - (lv) * (tv)                           \
                     + __logf(1.f + __expf(-al_));                            \
        num = fmaf(wgt_, bce_, num);                                          \
        den += wgt_;                                                          \
    }

/* one k-slot of the horizontal 31-window (verified bit-exact R7..R18) */
#define KSLOT(pk, pkm1, tv, lv, FIRST, LAST)                                  \
    {                                                                         \
        float hs_ = base_;                                                    \
        if (!(LAST)) {                                                        \
            float sa_ = __shfl_up(tot_ - (pk), 2);                            \
            hs_ += okm2 ? sa_ : 0.f;                                          \
        }                                                                     \
        if (!(FIRST)) {                                                       \
            float se_ = __shfl_down((pkm1), 2);                               \
            hs_ += okp2 ? se_ : 0.f;                                          \
        }                                                                     \
        EMIT(tv, lv, hs_)                                                     \
    }

/* full row: logits global load issued FIRST (longest latency), then LDS
   vertical sums + stashed raw t; horizontal window + BCE. */
#define ROWPASS(r)                                                            \
    {                                                                         \
        const float4* lp_ = (const float4*)(lb + (size_t)(y0 + (r)) * W + x0);\
        float4 La_ = lp_[0], Lb_ = lp_[1];                                    \
        float4 A_  = ((const float4*)vs[(r)])[2 * lane];                      \
        float4 B_  = ((const float4*)vs[(r)])[2 * lane + 1];                  \
        float4 Ta_ = ((const float4*)traw[(r)])[2 * lane];                    \
        float4 Tb_ = ((const float4*)traw[(r)])[2 * lane + 1];                \
        const float p0_ = A_.x;                                               \
        const float p1_ = p0_ + A_.y;                                         \
        const float p2_ = p1_ + A_.z;                                         \
        const float p3_ = p2_ + A_.w;                                         \
        const float p4_ = p3_ + B_.x;                                         \
        const float p5_ = p4_ + B_.y;                                         \
        const float p6_ = p5_ + B_.z;                                         \
        const float tot_ = p6_ + B_.w;                                        \
        const float bm_ = __shfl_up(tot_, 1);                                 \
        const float dp_ = __shfl_down(tot_, 1);                               \
        const float base_ = (okm1 ? bm_ : 0.f) + tot_ + (okp1 ? dp_ : 0.f);   \
        KSLOT(p0_, 0.f, Ta_.x, La_.x, 1, 0)                                   \
        KSLOT(p1_, p0_, Ta_.y, La_.y, 0, 0)                                   \
        KSLOT(p2_, p1_, Ta_.z, La_.z, 0, 0)                                   \
        KSLOT(p3_, p2_, Ta_.w, La_.w, 0, 0)                                   \
        KSLOT(p4_, p3_, Tb_.x, Lb_.x, 0, 0)                                   \
        KSLOT(p5_, p4_, Tb_.y, Lb_.y, 0, 0)                                   \
        KSLOT(p6_, p5_, Tb_.z, Lb_.z, 0, 0)                                   \
        KSLOT(0.f, p6_, Tb_.w, Lb_.w, 0, 1)                                   \
    }

/* ---------- Phase 1: vertical running windows into LDS ------------------ */
/* thread owns ONE column (tid); G=1 -> interior band, no guards.
   sched_barrier chunking is LOAD-BEARING (R16/R17: removal or a fused
   finalize tail -> minimal-pressure serial chain, 10x slowdown).
   Rows c=15..22 are the band's own rows (always in-bounds): stash raw
   value to traw so Phase 2 needs no global t re-read.                      */
#define P1_INIT(G, C0, C1)                                                    \
    _Pragma("unroll")                                                         \
    for (int c = (C0); c < (C1); ++c) {                                       \
        const int y = y0 + c - PAD;                                           \
        float a0 = 0.f;                                                       \
        if ((G) || (unsigned)y < (unsigned)H) a0 = tcol[y * W];               \
        run0 += a0;                                                           \
        if (c >= PAD && c < PAD + BAND) traw[c - PAD][tid] = a0;              \
    }

#define P1_SLIDE(G, J0, J1)                                                   \
    _Pragma("unroll")                                                         \
    for (int j = (J0); j < (J1); ++j) {                                       \
        vs[j][tid] = run0;                                                    \
        if (j < BAND - 1) {                                                   \
            const int ye = y0 + j + PAD + 1, yl = y0 + j - PAD;               \
            float e0 = 0.f, s0 = 0.f;                                         \
            if ((G) || (unsigned)ye < (unsigned)H) e0 = tcol[ye * W];         \
            if ((G) || (unsigned)yl < (unsigned)H) s0 = tcol[yl * W];         \
            run0 += e0 - s0;                                                  \
        }                                                                     \
    }

#define PHASE1(G)                                                             \
    P1_INIT(G, 0, 8)   __builtin_amdgcn_sched_barrier(0);                     \
    P1_INIT(G, 8, 16)  __builtin_amdgcn_sched_barrier(0);                     \
    P1_INIT(G, 16, 24) __builtin_amdgcn_sched_barrier(0);                     \
    P1_INIT(G, 24, 31) __builtin_amdgcn_sched_barrier(0);                     \
    P1_SLIDE(G, 0, 4)  __builtin_amdgcn_sched_barrier(0);                     \
    P1_SLIDE(G, 4, 8)

__global__ __launch_bounds__(NTHREADS)
void wbce_band_kernel(const float* __restrict__ logits,
                      const float* __restrict__ targets,
                      float2* __restrict__ partials) {
    __shared__ __align__(16) float vs[BAND][W];     /* 16 KB */
    __shared__ __align__(16) float traw[BAND][W];   /* 16 KB */

    const int tid  = threadIdx.x;
    const int lane = tid & 63;
    const int w    = tid >> 6;                    /* wave id 0..7 = row */

    /* XCD-aware bijective swizzle: 256 consecutive blocks (4 images) per XCD */
    const int bid  = (int)blockIdx.x;
    const int sbid = (bid & (NXCD - 1)) * (NBLOCKS / NXCD) + (bid >> 3);

    const int img  = sbid >> 6;            /* sbid / NBANDS */
    const int band = sbid & (NBANDS - 1);
    const int y0   = band * BAND;
    const int x0   = lane * 8;

    const float* tb = targets + (size_t)img * H * W;
    const float* lb = logits  + (size_t)img * H * W;
    const float* tcol = tb + tid;

    /* ---- Phase 1: cooperative vertical 31-row windows -> LDS ---- */
    float run0 = 0.f;
    if (y0 >= PAD && y0 + BAND + PAD - 1 < H) {
        PHASE1(1)
    } else {
        PHASE1(0)
    }
    __syncthreads();

    /* ---- Phase 2: horizontal window + fused weight/BCE (wave = 1 row) ---- */
    const bool okm2 = lane >= 2, okm1 = lane >= 1;
    const bool okp1 = lane <= 62, okp2 = lane <= 61;
    float num = 0.f, den = 0.f;

    ROWPASS(w)

    /* ---- wave reduction, one partial pair per wave ---- */
    #pragma unroll
    for (int off = 32; off > 0; off >>= 1) {
        num += __shfl_down(num, off);
        den += __shfl_down(den, off);
    }
    if (lane == 0) {
        partials[sbid * 8 + w] = make_float2(num, den);
    }
}

/* 16384 partial pairs -> scalar. Image i owns pairs [i*512, i*512+512). */
__global__ __launch_bounds__(1024)
void wbce_finalize_kernel(const float2* __restrict__ partials,
                          float* __restrict__ out) {
    __shared__ float rsum[16];
    const int t = threadIdx.x;
    const int img = t >> 5;
    const int j = t & 31;
    const int base = img * 512;
    float num = 0.f, den = 0.f;
    #pragma unroll
    for (int k = 0; k < 16; ++k) {
        float2 p = partials[base + j + 32 * k];
        num += p.x; den += p.y;
    }
    #pragma unroll
    for (int off = 16; off > 0; off >>= 1) {
        num += __shfl_down(num, off, 32);
        den += __shfl_down(den, off, 32);
    }
    float ratio = 0.f;
    if ((t & 31) == 0) ratio = num / den;
    ratio += __shfl_down(ratio, 32);          /* lane0 += lane32 */
    const int lane = t & 63;
    const int wv = t >> 6;
    if (lane == 0) rsum[wv] = ratio;
    __syncthreads();
    if (t == 0) {
        float s = 0.f;
        #pragma unroll
        for (int i = 0; i < 16; ++i) s += rsum[i];
        out[0] = s / (float)BATCH;
    }
}

extern "C" void kernel_launch(void* const* d_in, const int* in_sizes, int n_in,
                              void* d_out, int out_size, void* d_ws, size_t ws_size,
                              hipStream_t stream) {
    const float* logits  = (const float*)d_in[0];
    const float* targets = (const float*)d_in[1];
    float* out = (float*)d_out;
    float2* partials = (float2*)d_ws;   /* NPART float2 = 128 KB */

    wbce_band_kernel<<<NBLOCKS, NTHREADS, 0, stream>>>(logits, targets, partials);
    wbce_finalize_kernel<<<1, 1024, 0, stream>>>(partials, out);
}